// Round 3
// baseline (782.782 us; speedup 1.0000x reference)
//
#include <hip/hip_runtime.h>
#include <hip/hip_bf16.h>
#include <math.h>

#define B_ 4
#define H_ 8
#define N_ 2048
#define C_ 64
#define BM 64
#define BN 64
#define LDH 72   // padded LDS row stride (halves); 144B keeps 16B align, 2-way-max bank alias

typedef _Float16 half8 __attribute__((ext_vector_type(8)));
typedef _Float16 half4 __attribute__((ext_vector_type(4)));
typedef float f32x4 __attribute__((ext_vector_type(4)));

#if __has_builtin(__builtin_amdgcn_exp2f)
#define EXP2(x) __builtin_amdgcn_exp2f(x)
#else
#define EXP2(x) exp2f(x)
#endif

// ---------------- kernel 1: k_updated = k^2 * v * a_norm * exp(4*(1-s)) ----------------
// k_up = k*a2 = k^2*v*a/K_mat^2, K_mat=exp(-2(1-s)) -> 1/K_mat^2 = exp(+4(1-s))
// Emitted as hi/lo fp16 pair (hi = rn(x), lo = rn(x - hi)) for split-MFMA precision.
__global__ __launch_bounds__(512) void prep_kernel(
    const float* __restrict__ k,
    const float* __restrict__ v,
    const float* __restrict__ a_rand,
    _Float16* __restrict__ kup_hi,
    _Float16* __restrict__ kup_lo)
{
    int bn = blockIdx.x;              // b*N + n
    int b = bn >> 11, n = bn & (N_ - 1);
    int t = threadIdx.x;
    int h = t >> 6, c = t & 63;       // one wave == one head row (64 lanes == C)
    size_t idx = (((size_t)(b * H_ + h)) * N_ + n) * C_ + c;
    float kf = k[idx];
    float vf = v[idx];
    float af = a_rand[idx];
    float ks = kf * kf, vs = vf * vf;
    #pragma unroll
    for (int m = 1; m < 64; m <<= 1) {
        ks += __shfl_xor(ks, m, 64);
        vs += __shfl_xor(vs, m, 64);
    }
    float kinv = 1.0f / (1e-6f + sqrtf(ks));
    float vinv = 1.0f / (1e-6f + sqrtf(vs));
    __shared__ float a2s[H_][C_];
    a2s[h][c] = af * af;
    __syncthreads();
    float asum = 0.0f;
    #pragma unroll
    for (int hh = 0; hh < H_; hh++) asum += a2s[hh][c];
    float ainv = 1.0f / (1e-6f + sqrtf(asum));
    float s = fmaxf(kf * kinv * vf * vinv, 0.0f);
    // exp(4*(1-s)) == exp2(4*log2(e)*(1-s))
    float kupf = kf * kf * vf * (af * ainv) * EXP2(5.7707801635558535f * (1.0f - s));
    kupf = fminf(fmaxf(kupf, -60000.0f), 60000.0f);   // clamp BEFORE split: lo never saturates
    _Float16 hi = (_Float16)kupf;
    _Float16 lo = (_Float16)(kupf - (float)hi);
    kup_hi[idx] = hi;
    kup_lo[idx] = lo;
}

// ---------------- kernel 2: attn = softmax(q/8 . kup^T); out = attn . v ----------------
__global__ __launch_bounds__(256) void attn_kernel(
    const float* __restrict__ q,
    const float* __restrict__ v,
    const _Float16* __restrict__ kup_hi,
    const _Float16* __restrict__ kup_lo,
    float* __restrict__ out,     // f32 [B,H,N,C]
    float* __restrict__ attn)    // f32 [B,H,N,N]
{
    __shared__ __align__(16) _Float16 Qs[BM * LDH];
    __shared__ __align__(16) _Float16 Ql[BM * LDH];
    __shared__ __align__(16) _Float16 Ks[BN * LDH];
    __shared__ __align__(16) _Float16 Kl[BN * LDH];
    __shared__ __align__(16) _Float16 Vt[C_ * LDH];  // transposed V: [c][key]
    __shared__ __align__(16) _Float16 Ps[BM * LDH];

    int bh = blockIdx.x;
    int qb = blockIdx.y * BM;
    int t = threadIdx.x;
    int w = t >> 6, lane = t & 63;
    int quad = lane >> 4, lc = lane & 15;

    const size_t base = (size_t)bh * N_ * C_;
    const float* qg = q + base + (size_t)qb * C_;
    const _Float16* kgh = kup_hi + base;
    const _Float16* kgl = kup_lo + base;
    const float* vg = v + base;

    // stage Q hi/lo, scaled by log2(e)/8 (log2 domain: exp2 later == softmax(q.k/8))
    const float qscale = 0.18033688011112042f;
    #pragma unroll
    for (int it = 0; it < 4; it++) {
        int idx = it * 256 + t;
        int row = idx >> 4, seg = idx & 15;           // 16 float4 per 64-float row
        float4 d = *(const float4*)(qg + (size_t)row * C_ + seg * 4);
        float f0 = d.x * qscale, f1 = d.y * qscale, f2 = d.z * qscale, f3 = d.w * qscale;
        half4 hv, lv;
        hv[0] = (_Float16)f0; lv[0] = (_Float16)(f0 - (float)hv[0]);
        hv[1] = (_Float16)f1; lv[1] = (_Float16)(f1 - (float)hv[1]);
        hv[2] = (_Float16)f2; lv[2] = (_Float16)(f2 - (float)hv[2]);
        hv[3] = (_Float16)f3; lv[3] = (_Float16)(f3 - (float)hv[3]);
        *(half4*)&Qs[row * LDH + seg * 4] = hv;
        *(half4*)&Ql[row * LDH + seg * 4] = lv;
    }
    __syncthreads();

    // per-wave A fragments of Q (rows 16w..16w+15), kept all kernel
    // A-operand layout: A[m=lane&15][k=quad*8+j]
    half8 qa0 = *(half8*)&Qs[(w * 16 + lc) * LDH + 0 + quad * 8];
    half8 qa1 = *(half8*)&Qs[(w * 16 + lc) * LDH + 32 + quad * 8];
    half8 ql0 = *(half8*)&Ql[(w * 16 + lc) * LDH + 0 + quad * 8];
    half8 ql1 = *(half8*)&Ql[(w * 16 + lc) * LDH + 32 + quad * 8];

    float m_run[4], l_run[4];
    f32x4 Oacc[4];
    #pragma unroll
    for (int r = 0; r < 4; r++) { m_run[r] = -INFINITY; l_run[r] = 0.0f; }
    #pragma unroll
    for (int sc = 0; sc < 4; sc++) Oacc[sc] = (f32x4){0.f, 0.f, 0.f, 0.f};

    // ---- pass 1: row max + sumexp over all keys ----
    for (int j0 = 0; j0 < N_; j0 += BN) {
        __syncthreads();
        #pragma unroll
        for (int it = 0; it < 2; it++) {
            int idx = it * 256 + t;
            int row = idx >> 3, seg = idx & 7;        // 8 half8 per 64-half row
            *(half8*)&Ks[row * LDH + seg * 8] =
                *(const half8*)(kgh + (size_t)(j0 + row) * C_ + seg * 8);
            *(half8*)&Kl[row * LDH + seg * 8] =
                *(const half8*)(kgl + (size_t)(j0 + row) * C_ + seg * 8);
        }
        __syncthreads();
        f32x4 S[4];
        #pragma unroll
        for (int s = 0; s < 4; s++) {
            half8 bh0 = *(half8*)&Ks[(s * 16 + lc) * LDH + 0 + quad * 8];
            half8 bh1 = *(half8*)&Ks[(s * 16 + lc) * LDH + 32 + quad * 8];
            half8 bl0 = *(half8*)&Kl[(s * 16 + lc) * LDH + 0 + quad * 8];
            half8 bl1 = *(half8*)&Kl[(s * 16 + lc) * LDH + 32 + quad * 8];
            f32x4 acc = (f32x4){0.f, 0.f, 0.f, 0.f};
            acc = __builtin_amdgcn_mfma_f32_16x16x32_f16(qa0, bh0, acc, 0, 0, 0);
            acc = __builtin_amdgcn_mfma_f32_16x16x32_f16(qa1, bh1, acc, 0, 0, 0);
            acc = __builtin_amdgcn_mfma_f32_16x16x32_f16(qa0, bl0, acc, 0, 0, 0);
            acc = __builtin_amdgcn_mfma_f32_16x16x32_f16(qa1, bl1, acc, 0, 0, 0);
            acc = __builtin_amdgcn_mfma_f32_16x16x32_f16(ql0, bh0, acc, 0, 0, 0);
            acc = __builtin_amdgcn_mfma_f32_16x16x32_f16(ql1, bh1, acc, 0, 0, 0);
            S[s] = acc;
        }
        // C/D layout: row = quad*4+r, col = s*16+lc. Reduce over cols (lc within quad).
        #pragma unroll
        for (int r = 0; r < 4; r++) {
            float mloc = fmaxf(fmaxf(S[0][r], S[1][r]), fmaxf(S[2][r], S[3][r]));
            #pragma unroll
            for (int msk = 1; msk < 16; msk <<= 1)
                mloc = fmaxf(mloc, __shfl_xor(mloc, msk, 64));
            float mnew = fmaxf(m_run[r], mloc);
            float rs = EXP2(S[0][r] - mnew) + EXP2(S[1][r] - mnew) +
                       EXP2(S[2][r] - mnew) + EXP2(S[3][r] - mnew);
            #pragma unroll
            for (int msk = 1; msk < 16; msk <<= 1)
                rs += __shfl_xor(rs, msk, 64);
            l_run[r] = l_run[r] * EXP2(m_run[r] - mnew) + rs;
            m_run[r] = mnew;
        }
    }
    float linv[4];
    #pragma unroll
    for (int r = 0; r < 4; r++) linv[r] = 1.0f / l_run[r];

    float* attng = attn + (size_t)bh * N_ * N_ + (size_t)qb * N_;

    // ---- pass 2: recompute scores (bitwise-identical), write attn, accumulate O = P.V ----
    for (int j0 = 0; j0 < N_; j0 += BN) {
        __syncthreads();
        #pragma unroll
        for (int it = 0; it < 2; it++) {
            int idx = it * 256 + t;
            int row = idx >> 3, seg = idx & 7;
            *(half8*)&Ks[row * LDH + seg * 8] =
                *(const half8*)(kgh + (size_t)(j0 + row) * C_ + seg * 8);
            *(half8*)&Kl[row * LDH + seg * 8] =
                *(const half8*)(kgl + (size_t)(j0 + row) * C_ + seg * 8);
        }
        {   // stage V transposed: Vt[c][key], fp32 -> fp16
            int key = t >> 2, cb = (t & 3) * 16;
            const float* vr = vg + (size_t)(j0 + key) * C_ + cb;
            #pragma unroll
            for (int i = 0; i < 16; i += 4) {
                float4 d = *(const float4*)(vr + i);
                Vt[(cb + i + 0) * LDH + key] = (_Float16)d.x;
                Vt[(cb + i + 1) * LDH + key] = (_Float16)d.y;
                Vt[(cb + i + 2) * LDH + key] = (_Float16)d.z;
                Vt[(cb + i + 3) * LDH + key] = (_Float16)d.w;
            }
        }
        __syncthreads();
        f32x4 S[4];
        #pragma unroll
        for (int s = 0; s < 4; s++) {
            half8 bh0 = *(half8*)&Ks[(s * 16 + lc) * LDH + 0 + quad * 8];
            half8 bh1 = *(half8*)&Ks[(s * 16 + lc) * LDH + 32 + quad * 8];
            half8 bl0 = *(half8*)&Kl[(s * 16 + lc) * LDH + 0 + quad * 8];
            half8 bl1 = *(half8*)&Kl[(s * 16 + lc) * LDH + 32 + quad * 8];
            f32x4 acc = (f32x4){0.f, 0.f, 0.f, 0.f};
            acc = __builtin_amdgcn_mfma_f32_16x16x32_f16(qa0, bh0, acc, 0, 0, 0);
            acc = __builtin_amdgcn_mfma_f32_16x16x32_f16(qa1, bh1, acc, 0, 0, 0);
            acc = __builtin_amdgcn_mfma_f32_16x16x32_f16(qa0, bl0, acc, 0, 0, 0);
            acc = __builtin_amdgcn_mfma_f32_16x16x32_f16(qa1, bl1, acc, 0, 0, 0);
            acc = __builtin_amdgcn_mfma_f32_16x16x32_f16(ql0, bh0, acc, 0, 0, 0);
            acc = __builtin_amdgcn_mfma_f32_16x16x32_f16(ql1, bh1, acc, 0, 0, 0);
            S[s] = acc;
        }
        #pragma unroll
        for (int s = 0; s < 4; s++) {
            #pragma unroll
            for (int r = 0; r < 4; r++) {
                float p = EXP2(S[s][r] - m_run[r]) * linv[r];
                Ps[(w * 16 + quad * 4 + r) * LDH + s * 16 + lc] = (_Float16)p;
            }
        }
        __syncthreads();   // Ps complete block-wide
        // PV: A-frag = P rows (m=16w+lc), k = key; B-frag = Vt rows (n=c=16sc+lc), k = key
        #pragma unroll
        for (int kn = 0; kn < 2; kn++) {
            half8 pa = *(half8*)&Ps[(w * 16 + lc) * LDH + kn * 32 + quad * 8];
            #pragma unroll
            for (int sc = 0; sc < 4; sc++) {
                half8 vb = *(half8*)&Vt[(sc * 16 + lc) * LDH + kn * 32 + quad * 8];
                Oacc[sc] = __builtin_amdgcn_mfma_f32_16x16x32_f16(pa, vb, Oacc[sc], 0, 0, 0);
            }
        }
        // coalesced attn write (fp32)
        #pragma unroll
        for (int it = 0; it < 4; it++) {
            int idx = it * 256 + t;
            int row = idx >> 4, seg = idx & 15;
            half4 hv = *(half4*)&Ps[row * LDH + seg * 4];
            float4 o;
            o.x = (float)hv[0];
            o.y = (float)hv[1];
            o.z = (float)hv[2];
            o.w = (float)hv[3];
            *(float4*)(attng + (size_t)row * N_ + j0 + seg * 4) = o;
        }
    }

    // write O (fp32); C/D layout: row = quad*4+r, col = 16sc+lc
    float* og = out + base + (size_t)qb * C_;
    #pragma unroll
    for (int sc = 0; sc < 4; sc++) {
        #pragma unroll
        for (int r = 0; r < 4; r++) {
            og[(size_t)(w * 16 + quad * 4 + r) * C_ + sc * 16 + lc] = Oacc[sc][r];
        }
    }
}

extern "C" void kernel_launch(void* const* d_in, const int* in_sizes, int n_in,
                              void* d_out, int out_size, void* d_ws, size_t ws_size,
                              hipStream_t stream) {
    const float* q = (const float*)d_in[0];
    const float* k = (const float*)d_in[1];
    const float* v = (const float*)d_in[2];
    const float* a = (const float*)d_in[3];
    const size_t nelem = (size_t)B_ * H_ * N_ * C_;   // 4M
    _Float16* kup_hi = (_Float16*)d_ws;               // 8 MB
    _Float16* kup_lo = kup_hi + nelem;                // 8 MB
    float* out = (float*)d_out;
    float* attn = out + nelem;

    prep_kernel<<<dim3(B_ * N_), dim3(512), 0, stream>>>(k, v, a, kup_hi, kup_lo);
    attn_kernel<<<dim3(B_ * H_, N_ / BM), dim3(256), 0, stream>>>(q, v, kup_hi, kup_lo, out, attn);
}

// Round 4
// 749.457 us; speedup vs baseline: 1.0445x; 1.0445x over previous
//
#include <hip/hip_runtime.h>
#include <hip/hip_bf16.h>
#include <math.h>

#define B_ 4
#define H_ 8
#define N_ 2048
#define C_ 64
#define BM 64
#define BN 64
#define LDH 72   // padded LDS row stride (halves)

typedef _Float16 half8 __attribute__((ext_vector_type(8)));
typedef _Float16 half4 __attribute__((ext_vector_type(4)));
typedef float f32x4 __attribute__((ext_vector_type(4)));

#if __has_builtin(__builtin_amdgcn_exp2f)
#define EXP2(x) __builtin_amdgcn_exp2f(x)
#else
#define EXP2(x) exp2f(x)
#endif

// ---------------- kernel 1: k_updated = k^2 * v * a_norm * exp(4*(1-s)) ----------------
__global__ __launch_bounds__(512) void prep_kernel(
    const float* __restrict__ k,
    const float* __restrict__ v,
    const float* __restrict__ a_rand,
    _Float16* __restrict__ kup_hi,
    _Float16* __restrict__ kup_lo)
{
    int bn = blockIdx.x;              // b*N + n
    int b = bn >> 11, n = bn & (N_ - 1);
    int t = threadIdx.x;
    int h = t >> 6, c = t & 63;       // one wave == one head row (64 lanes == C)
    size_t idx = (((size_t)(b * H_ + h)) * N_ + n) * C_ + c;
    float kf = k[idx];
    float vf = v[idx];
    float af = a_rand[idx];
    float ks = kf * kf, vs = vf * vf;
    #pragma unroll
    for (int m = 1; m < 64; m <<= 1) {
        ks += __shfl_xor(ks, m, 64);
        vs += __shfl_xor(vs, m, 64);
    }
    float kinv = 1.0f / (1e-6f + sqrtf(ks));
    float vinv = 1.0f / (1e-6f + sqrtf(vs));
    __shared__ float a2s[H_][C_];
    a2s[h][c] = af * af;
    __syncthreads();
    float asum = 0.0f;
    #pragma unroll
    for (int hh = 0; hh < H_; hh++) asum += a2s[hh][c];
    float ainv = 1.0f / (1e-6f + sqrtf(asum));
    float s = fmaxf(kf * kinv * vf * vinv, 0.0f);
    float kupf = kf * kf * vf * (af * ainv) * EXP2(5.7707801635558535f * (1.0f - s));
    kupf = fminf(fmaxf(kupf, -60000.0f), 60000.0f);   // clamp BEFORE split
    _Float16 hi = (_Float16)kupf;
    _Float16 lo = (_Float16)(kupf - (float)hi);
    kup_hi[idx] = hi;
    kup_lo[idx] = lo;
}

// ---------------- kernel 2: attn = softmax(q/8 . kup^T); out = attn . v ----------------
__global__ __launch_bounds__(256, 4) void attn_kernel(
    const float* __restrict__ q,
    const float* __restrict__ v,
    const _Float16* __restrict__ kup_hi,
    const _Float16* __restrict__ kup_lo,
    float* __restrict__ out,     // f32 [B,H,N,C]
    float* __restrict__ attn)    // f32 [B,H,N,N]
{
    // KQh/KQl hold Q hi/lo during startup, then K tiles (Q frags live in regs).
    __shared__ __align__(16) _Float16 KQh[BM * LDH];
    __shared__ __align__(16) _Float16 KQl[BM * LDH];
    __shared__ __align__(16) _Float16 Vt[C_ * LDH + 64];  // swizzled transposed V
    __shared__ __align__(16) _Float16 Ps[BM * LDH];

    int bh = blockIdx.x;
    int qb = blockIdx.y * BM;
    int t = threadIdx.x;
    int w = t >> 6, lane = t & 63;
    int quad = lane >> 4, lc = lane & 15;

    const size_t base = (size_t)bh * N_ * C_;
    const float* qg = q + base + (size_t)qb * C_;
    const _Float16* kgh = kup_hi + base;
    const _Float16* kgl = kup_lo + base;
    const float* vg = v + base;

    // stage Q hi/lo, scaled by log2(e)/8
    const float qscale = 0.18033688011112042f;
    #pragma unroll
    for (int it = 0; it < 4; it++) {
        int idx = it * 256 + t;
        int row = idx >> 4, seg = idx & 15;
        float4 d = *(const float4*)(qg + (size_t)row * C_ + seg * 4);
        float f0 = d.x * qscale, f1 = d.y * qscale, f2 = d.z * qscale, f3 = d.w * qscale;
        half4 hv, lv;
        hv[0] = (_Float16)f0; lv[0] = (_Float16)(f0 - (float)hv[0]);
        hv[1] = (_Float16)f1; lv[1] = (_Float16)(f1 - (float)hv[1]);
        hv[2] = (_Float16)f2; lv[2] = (_Float16)(f2 - (float)hv[2]);
        hv[3] = (_Float16)f3; lv[3] = (_Float16)(f3 - (float)hv[3]);
        *(half4*)&KQh[row * LDH + seg * 4] = hv;
        *(half4*)&KQl[row * LDH + seg * 4] = lv;
    }
    __syncthreads();

    // per-wave A fragments of Q (rows 16w..16w+15): A[m=lc][k=quad*8+j]
    half8 qa0 = *(half8*)&KQh[(w * 16 + lc) * LDH + 0 + quad * 8];
    half8 qa1 = *(half8*)&KQh[(w * 16 + lc) * LDH + 32 + quad * 8];
    half8 ql0 = *(half8*)&KQl[(w * 16 + lc) * LDH + 0 + quad * 8];
    half8 ql1 = *(half8*)&KQl[(w * 16 + lc) * LDH + 32 + quad * 8];

    float m_run[4], l_run[4];
    f32x4 Oacc[4];
    #pragma unroll
    for (int r = 0; r < 4; r++) { m_run[r] = -INFINITY; l_run[r] = 0.0f; }
    #pragma unroll
    for (int sc = 0; sc < 4; sc++) Oacc[sc] = (f32x4){0.f, 0.f, 0.f, 0.f};

    // ---- pass 1: per-lane online max/sumexp (no per-iter shuffles) ----
    for (int j0 = 0; j0 < N_; j0 += BN) {
        __syncthreads();   // also protects Q-frag reads on first iter
        #pragma unroll
        for (int it = 0; it < 2; it++) {
            int idx = it * 256 + t;
            int row = idx >> 3, seg = idx & 7;
            *(half8*)&KQh[row * LDH + seg * 8] =
                *(const half8*)(kgh + (size_t)(j0 + row) * C_ + seg * 8);
            *(half8*)&KQl[row * LDH + seg * 8] =
                *(const half8*)(kgl + (size_t)(j0 + row) * C_ + seg * 8);
        }
        __syncthreads();
        f32x4 S[4];
        #pragma unroll
        for (int s = 0; s < 4; s++) {
            half8 bh0 = *(half8*)&KQh[(s * 16 + lc) * LDH + 0 + quad * 8];
            half8 bh1 = *(half8*)&KQh[(s * 16 + lc) * LDH + 32 + quad * 8];
            half8 bl0 = *(half8*)&KQl[(s * 16 + lc) * LDH + 0 + quad * 8];
            half8 bl1 = *(half8*)&KQl[(s * 16 + lc) * LDH + 32 + quad * 8];
            f32x4 acc = (f32x4){0.f, 0.f, 0.f, 0.f};
            acc = __builtin_amdgcn_mfma_f32_16x16x32_f16(qa0, bh0, acc, 0, 0, 0);
            acc = __builtin_amdgcn_mfma_f32_16x16x32_f16(qa1, bh1, acc, 0, 0, 0);
            acc = __builtin_amdgcn_mfma_f32_16x16x32_f16(qa0, bl0, acc, 0, 0, 0);
            acc = __builtin_amdgcn_mfma_f32_16x16x32_f16(qa1, bl1, acc, 0, 0, 0);
            acc = __builtin_amdgcn_mfma_f32_16x16x32_f16(ql0, bh0, acc, 0, 0, 0);
            acc = __builtin_amdgcn_mfma_f32_16x16x32_f16(ql1, bh1, acc, 0, 0, 0);
            S[s] = acc;
        }
        #pragma unroll
        for (int r = 0; r < 4; r++) {
            float mloc = fmaxf(fmaxf(S[0][r], S[1][r]), fmaxf(S[2][r], S[3][r]));
            float mnew = fmaxf(m_run[r], mloc);
            float rs = EXP2(S[0][r] - mnew) + EXP2(S[1][r] - mnew) +
                       EXP2(S[2][r] - mnew) + EXP2(S[3][r] - mnew);
            l_run[r] = l_run[r] * EXP2(m_run[r] - mnew) + rs;
            m_run[r] = mnew;
        }
    }
    // cross-lane merge over the 16 lc lanes (rows live per quad)
    #pragma unroll
    for (int r = 0; r < 4; r++) {
        float m = m_run[r], l = l_run[r];
        #pragma unroll
        for (int msk = 1; msk < 16; msk <<= 1) {
            float mo = __shfl_xor(m, msk, 64);
            float lo = __shfl_xor(l, msk, 64);
            float mn = fmaxf(m, mo);
            l = l * EXP2(m - mn) + lo * EXP2(mo - mn);
            m = mn;
        }
        m_run[r] = m;
        l_run[r] = 1.0f / l;   // store inverse
    }

    float* attng = attn + (size_t)bh * N_ * N_ + (size_t)qb * N_;

    // ---- pass 2: recompute scores, write attn, accumulate O = P.V ----
    for (int j0 = 0; j0 < N_; j0 += BN) {
        __syncthreads();
        #pragma unroll
        for (int it = 0; it < 2; it++) {
            int idx = it * 256 + t;
            int row = idx >> 3, seg = idx & 7;
            *(half8*)&KQh[row * LDH + seg * 8] =
                *(const half8*)(kgh + (size_t)(j0 + row) * C_ + seg * 8);
            *(half8*)&KQl[row * LDH + seg * 8] =
                *(const half8*)(kgl + (size_t)(j0 + row) * C_ + seg * 8);
        }
        {   // stage V transposed + bank-swizzled: Vt[c][key] at c*LDH + ((c>>4)&3)*16 + key
            int key = t >> 2, cb = (t & 3) * 16;
            int ofs = (t & 3) * 16;   // == ((c>>4)&3)*16 for c in [cb, cb+16)
            const float* vr = vg + (size_t)(j0 + key) * C_ + cb;
            #pragma unroll
            for (int i = 0; i < 16; i += 4) {
                float4 d = *(const float4*)(vr + i);
                Vt[(cb + i + 0) * LDH + ofs + key] = (_Float16)d.x;
                Vt[(cb + i + 1) * LDH + ofs + key] = (_Float16)d.y;
                Vt[(cb + i + 2) * LDH + ofs + key] = (_Float16)d.z;
                Vt[(cb + i + 3) * LDH + ofs + key] = (_Float16)d.w;
            }
        }
        __syncthreads();
        f32x4 S[4];
        #pragma unroll
        for (int s = 0; s < 4; s++) {
            half8 bh0 = *(half8*)&KQh[(s * 16 + lc) * LDH + 0 + quad * 8];
            half8 bh1 = *(half8*)&KQh[(s * 16 + lc) * LDH + 32 + quad * 8];
            half8 bl0 = *(half8*)&KQl[(s * 16 + lc) * LDH + 0 + quad * 8];
            half8 bl1 = *(half8*)&KQl[(s * 16 + lc) * LDH + 32 + quad * 8];
            f32x4 acc = (f32x4){0.f, 0.f, 0.f, 0.f};
            acc = __builtin_amdgcn_mfma_f32_16x16x32_f16(qa0, bh0, acc, 0, 0, 0);
            acc = __builtin_amdgcn_mfma_f32_16x16x32_f16(qa1, bh1, acc, 0, 0, 0);
            acc = __builtin_amdgcn_mfma_f32_16x16x32_f16(qa0, bl0, acc, 0, 0, 0);
            acc = __builtin_amdgcn_mfma_f32_16x16x32_f16(qa1, bl1, acc, 0, 0, 0);
            acc = __builtin_amdgcn_mfma_f32_16x16x32_f16(ql0, bh0, acc, 0, 0, 0);
            acc = __builtin_amdgcn_mfma_f32_16x16x32_f16(ql1, bh1, acc, 0, 0, 0);
            S[s] = acc;
        }
        #pragma unroll
        for (int s = 0; s < 4; s++) {
            #pragma unroll
            for (int r = 0; r < 4; r++) {
                float p = EXP2(S[s][r] - m_run[r]) * l_run[r];
                Ps[(w * 16 + quad * 4 + r) * LDH + s * 16 + lc] = (_Float16)p;
            }
        }
        __syncthreads();   // Ps complete block-wide
        // PV: A-frag = P rows (m=16w+lc); B-frag = Vt rows (n=c=16sc+lc), swizzled
        #pragma unroll
        for (int kn = 0; kn < 2; kn++) {
            half8 pa = *(half8*)&Ps[(w * 16 + lc) * LDH + kn * 32 + quad * 8];
            #pragma unroll
            for (int sc = 0; sc < 4; sc++) {
                half8 vb = *(half8*)&Vt[(sc * 16 + lc) * LDH + sc * 16 + kn * 32 + quad * 8];
                Oacc[sc] = __builtin_amdgcn_mfma_f32_16x16x32_f16(pa, vb, Oacc[sc], 0, 0, 0);
            }
        }
        // coalesced attn write (fp32)
        #pragma unroll
        for (int it = 0; it < 4; it++) {
            int idx = it * 256 + t;
            int row = idx >> 4, seg = idx & 15;
            half4 hv = *(half4*)&Ps[row * LDH + seg * 4];
            float4 o;
            o.x = (float)hv[0];
            o.y = (float)hv[1];
            o.z = (float)hv[2];
            o.w = (float)hv[3];
            *(float4*)(attng + (size_t)row * N_ + j0 + seg * 4) = o;
        }
    }

    // write O (fp32); C/D layout: row = quad*4+r, col = 16sc+lc
    float* og = out + base + (size_t)qb * C_;
    #pragma unroll
    for (int sc = 0; sc < 4; sc++) {
        #pragma unroll
        for (int r = 0; r < 4; r++) {
            og[(size_t)(w * 16 + quad * 4 + r) * C_ + sc * 16 + lc] = Oacc[sc][r];
        }
    }
}

extern "C" void kernel_launch(void* const* d_in, const int* in_sizes, int n_in,
                              void* d_out, int out_size, void* d_ws, size_t ws_size,
                              hipStream_t stream) {
    const float* q = (const float*)d_in[0];
    const float* k = (const float*)d_in[1];
    const float* v = (const float*)d_in[2];
    const float* a = (const float*)d_in[3];
    const size_t nelem = (size_t)B_ * H_ * N_ * C_;   // 4M
    _Float16* kup_hi = (_Float16*)d_ws;               // 8 MB
    _Float16* kup_lo = kup_hi + nelem;                // 8 MB
    float* out = (float*)d_out;
    float* attn = out + nelem;

    prep_kernel<<<dim3(B_ * N_), dim3(512), 0, stream>>>(k, v, a, kup_hi, kup_lo);
    attn_kernel<<<dim3(B_ * H_, N_ / BM), dim3(256), 0, stream>>>(q, v, kup_hi, kup_lo, out, attn);
}

// Round 5
// 713.963 us; speedup vs baseline: 1.0964x; 1.0497x over previous
//
#include <hip/hip_runtime.h>
#include <hip/hip_bf16.h>
#include <math.h>

#define B_ 4
#define H_ 8
#define N_ 2048
#define C_ 64
#define BM 64
#define BN 64
#define LDH 72   // padded LDS row stride (halves), 144 B: 16B-aligned rows

typedef _Float16 half8 __attribute__((ext_vector_type(8)));
typedef _Float16 half4 __attribute__((ext_vector_type(4)));
typedef float f32x4 __attribute__((ext_vector_type(4)));

#if __has_builtin(__builtin_amdgcn_exp2f)
#define EXP2(x) __builtin_amdgcn_exp2f(x)
#else
#define EXP2(x) exp2f(x)
#endif

// ---------------- kernel 1: k_updated = k^2 * v * a_norm * exp(4*(1-s)), hi/lo fp16 ----------------
__global__ __launch_bounds__(512) void prep_kernel(
    const float* __restrict__ k,
    const float* __restrict__ v,
    const float* __restrict__ a_rand,
    _Float16* __restrict__ kup_hi,
    _Float16* __restrict__ kup_lo)
{
    int bn = blockIdx.x;              // b*N + n
    int b = bn >> 11, n = bn & (N_ - 1);
    int t = threadIdx.x;
    int h = t >> 6, c = t & 63;       // one wave == one head row (64 lanes == C)
    size_t idx = (((size_t)(b * H_ + h)) * N_ + n) * C_ + c;
    float kf = k[idx];
    float vf = v[idx];
    float af = a_rand[idx];
    float ks = kf * kf, vs = vf * vf;
    #pragma unroll
    for (int m = 1; m < 64; m <<= 1) {
        ks += __shfl_xor(ks, m, 64);
        vs += __shfl_xor(vs, m, 64);
    }
    float kinv = 1.0f / (1e-6f + sqrtf(ks));
    float vinv = 1.0f / (1e-6f + sqrtf(vs));
    __shared__ float a2s[H_][C_];
    a2s[h][c] = af * af;
    __syncthreads();
    float asum = 0.0f;
    #pragma unroll
    for (int hh = 0; hh < H_; hh++) asum += a2s[hh][c];
    float ainv = 1.0f / (1e-6f + sqrtf(asum));
    float s = fmaxf(kf * kinv * vf * vinv, 0.0f);
    float kupf = kf * kf * vf * (af * ainv) * EXP2(5.7707801635558535f * (1.0f - s));
    kupf = fminf(fmaxf(kupf, -60000.0f), 60000.0f);   // clamp BEFORE split
    _Float16 hi = (_Float16)kupf;
    _Float16 lo = (_Float16)(kupf - (float)hi);
    kup_hi[idx] = hi;
    kup_lo[idx] = lo;
}

// ---------------- kernel 1b: vt[bh][c][n] = (fp16) v[bh][n][c] ----------------
__global__ __launch_bounds__(256) void transpose_v_kernel(
    const float* __restrict__ v,
    _Float16* __restrict__ vt)
{
    __shared__ _Float16 T[C_ * LDH];
    int bh = blockIdx.x;
    int n0 = blockIdx.y * 64;
    int t = threadIdx.x;
    {   // load 64n x 64c fp32 tile, store transposed into LDS
        int nl = t >> 2, cs = (t & 3) * 16;
        const float* src = v + (size_t)bh * N_ * C_ + (size_t)(n0 + nl) * C_ + cs;
        #pragma unroll
        for (int i = 0; i < 16; i += 4) {
            float4 d = *(const float4*)(src + i);
            T[(cs + i + 0) * LDH + nl] = (_Float16)d.x;
            T[(cs + i + 1) * LDH + nl] = (_Float16)d.y;
            T[(cs + i + 2) * LDH + nl] = (_Float16)d.z;
            T[(cs + i + 3) * LDH + nl] = (_Float16)d.w;
        }
    }
    __syncthreads();
    #pragma unroll
    for (int it = 0; it < 2; it++) {
        int idx = it * 256 + t;
        int c = idx >> 3, seg = idx & 7;
        *(half8*)(vt + (size_t)bh * C_ * N_ + (size_t)c * N_ + n0 + seg * 8) =
            *(half8*)&T[c * LDH + seg * 8];
    }
}

// ---------------- kernel 2: attn = softmax(q/8 . kup^T); out = attn . v ----------------
__global__ __launch_bounds__(256, 3) void attn_kernel(
    const float* __restrict__ q,
    const _Float16* __restrict__ vt,      // fp16 [bh][c][n]
    const _Float16* __restrict__ kup_hi,
    const _Float16* __restrict__ kup_lo,
    float* __restrict__ out,     // f32 [B,H,N,C]
    float* __restrict__ attn)    // f32 [B,H,N,N]
{
    // KQh/KQl hold Q hi/lo during startup, then K tiles (Q frags live in regs).
    __shared__ __align__(16) _Float16 KQh[BM * LDH];
    __shared__ __align__(16) _Float16 KQl[BM * LDH];
    __shared__ __align__(16) _Float16 Vt[C_ * LDH];   // [c][key]
    __shared__ __align__(16) _Float16 Ps[BM * LDH];   // wave-private rows

    int bh = blockIdx.x;
    int qb = blockIdx.y * BM;
    int t = threadIdx.x;
    int w = t >> 6, lane = t & 63;
    int quad = lane >> 4, lc = lane & 15;

    const size_t base = (size_t)bh * N_ * C_;
    const float* qg = q + base + (size_t)qb * C_;
    const _Float16* kgh = kup_hi + base;
    const _Float16* kgl = kup_lo + base;
    const _Float16* vtg = vt + base;      // [c][n], c-major

    // per-thread staging map: two rows per thread (r0, r1), 8-half segment s0
    const int r0 = t >> 3, r1 = 32 + (t >> 3);
    const int s0 = (t & 7) * 8;

    // stage Q hi/lo, scaled by log2(e)/8
    const float qscale = 0.18033688011112042f;
    #pragma unroll
    for (int it = 0; it < 4; it++) {
        int idx = it * 256 + t;
        int row = idx >> 4, seg = idx & 15;
        float4 d = *(const float4*)(qg + (size_t)row * C_ + seg * 4);
        float f0 = d.x * qscale, f1 = d.y * qscale, f2 = d.z * qscale, f3 = d.w * qscale;
        half4 hv, lv;
        hv[0] = (_Float16)f0; lv[0] = (_Float16)(f0 - (float)hv[0]);
        hv[1] = (_Float16)f1; lv[1] = (_Float16)(f1 - (float)hv[1]);
        hv[2] = (_Float16)f2; lv[2] = (_Float16)(f2 - (float)hv[2]);
        hv[3] = (_Float16)f3; lv[3] = (_Float16)(f3 - (float)hv[3]);
        *(half4*)&KQh[row * LDH + seg * 4] = hv;
        *(half4*)&KQl[row * LDH + seg * 4] = lv;
    }
    __syncthreads();

    // per-wave A fragments of Q (rows 16w..16w+15): A[m=lc][k=quad*8+j]
    half8 qa0 = *(half8*)&KQh[(w * 16 + lc) * LDH + 0 + quad * 8];
    half8 qa1 = *(half8*)&KQh[(w * 16 + lc) * LDH + 32 + quad * 8];
    half8 ql0 = *(half8*)&KQl[(w * 16 + lc) * LDH + 0 + quad * 8];
    half8 ql1 = *(half8*)&KQl[(w * 16 + lc) * LDH + 32 + quad * 8];

    float m_run[4], l_run[4];
    f32x4 Oacc[4];
    #pragma unroll
    for (int r = 0; r < 4; r++) { m_run[r] = -INFINITY; l_run[r] = 0.0f; }
    #pragma unroll
    for (int sc = 0; sc < 4; sc++) Oacc[sc] = (f32x4){0.f, 0.f, 0.f, 0.f};

    // K-tile register prefetch (software pipeline)
    half8 pk0h, pk1h, pk0l, pk1l, pv0, pv1;
    pk0h = *(const half8*)(kgh + (size_t)r0 * C_ + s0);
    pk1h = *(const half8*)(kgh + (size_t)r1 * C_ + s0);
    pk0l = *(const half8*)(kgl + (size_t)r0 * C_ + s0);
    pk1l = *(const half8*)(kgl + (size_t)r1 * C_ + s0);

    // ---- pass 1: per-lane online max/sumexp ----
    for (int j0 = 0; j0 < N_; j0 += BN) {
        __syncthreads();   // prev readers done (also Q-frag reads first iter)
        *(half8*)&KQh[r0 * LDH + s0] = pk0h;
        *(half8*)&KQh[r1 * LDH + s0] = pk1h;
        *(half8*)&KQl[r0 * LDH + s0] = pk0l;
        *(half8*)&KQl[r1 * LDH + s0] = pk1l;
        if (j0 + BN < N_) {   // prefetch next tile; latency hides under compute
            pk0h = *(const half8*)(kgh + (size_t)(j0 + BN + r0) * C_ + s0);
            pk1h = *(const half8*)(kgh + (size_t)(j0 + BN + r1) * C_ + s0);
            pk0l = *(const half8*)(kgl + (size_t)(j0 + BN + r0) * C_ + s0);
            pk1l = *(const half8*)(kgl + (size_t)(j0 + BN + r1) * C_ + s0);
        }
        __syncthreads();
        f32x4 S[4];
        #pragma unroll
        for (int s = 0; s < 4; s++) {
            half8 bh0 = *(half8*)&KQh[(s * 16 + lc) * LDH + 0 + quad * 8];
            half8 bh1 = *(half8*)&KQh[(s * 16 + lc) * LDH + 32 + quad * 8];
            half8 bl0 = *(half8*)&KQl[(s * 16 + lc) * LDH + 0 + quad * 8];
            half8 bl1 = *(half8*)&KQl[(s * 16 + lc) * LDH + 32 + quad * 8];
            f32x4 acc = (f32x4){0.f, 0.f, 0.f, 0.f};
            acc = __builtin_amdgcn_mfma_f32_16x16x32_f16(qa0, bh0, acc, 0, 0, 0);
            acc = __builtin_amdgcn_mfma_f32_16x16x32_f16(qa1, bh1, acc, 0, 0, 0);
            acc = __builtin_amdgcn_mfma_f32_16x16x32_f16(qa0, bl0, acc, 0, 0, 0);
            acc = __builtin_amdgcn_mfma_f32_16x16x32_f16(qa1, bl1, acc, 0, 0, 0);
            acc = __builtin_amdgcn_mfma_f32_16x16x32_f16(ql0, bh0, acc, 0, 0, 0);
            acc = __builtin_amdgcn_mfma_f32_16x16x32_f16(ql1, bh1, acc, 0, 0, 0);
            S[s] = acc;
        }
        #pragma unroll
        for (int r = 0; r < 4; r++) {
            float mloc = fmaxf(fmaxf(S[0][r], S[1][r]), fmaxf(S[2][r], S[3][r]));
            float mnew = fmaxf(m_run[r], mloc);
            float rs = EXP2(S[0][r] - mnew) + EXP2(S[1][r] - mnew) +
                       EXP2(S[2][r] - mnew) + EXP2(S[3][r] - mnew);
            l_run[r] = l_run[r] * EXP2(m_run[r] - mnew) + rs;
            m_run[r] = mnew;
        }
    }
    // cross-lane merge over the 16 lc lanes (rows live per quad)
    #pragma unroll
    for (int r = 0; r < 4; r++) {
        float m = m_run[r], l = l_run[r];
        #pragma unroll
        for (int msk = 1; msk < 16; msk <<= 1) {
            float mo = __shfl_xor(m, msk, 64);
            float lo = __shfl_xor(l, msk, 64);
            float mn = fmaxf(m, mo);
            l = l * EXP2(m - mn) + lo * EXP2(mo - mn);
            m = mn;
        }
        m_run[r] = m;
        l_run[r] = 1.0f / l;   // store inverse
    }

    float* attng = attn + (size_t)bh * N_ * N_ + (size_t)qb * N_;

    // prefetch tile 0 for pass 2 (K + V)
    pk0h = *(const half8*)(kgh + (size_t)r0 * C_ + s0);
    pk1h = *(const half8*)(kgh + (size_t)r1 * C_ + s0);
    pk0l = *(const half8*)(kgl + (size_t)r0 * C_ + s0);
    pk1l = *(const half8*)(kgl + (size_t)r1 * C_ + s0);
    pv0  = *(const half8*)(vtg + (size_t)r0 * N_ + s0);
    pv1  = *(const half8*)(vtg + (size_t)r1 * N_ + s0);

    // ---- pass 2: recompute scores (bitwise-identical), write attn, accumulate O = P.V ----
    for (int j0 = 0; j0 < N_; j0 += BN) {
        __syncthreads();   // prev iter's K/Vt readers done
        *(half8*)&KQh[r0 * LDH + s0] = pk0h;
        *(half8*)&KQh[r1 * LDH + s0] = pk1h;
        *(half8*)&KQl[r0 * LDH + s0] = pk0l;
        *(half8*)&KQl[r1 * LDH + s0] = pk1l;
        *(half8*)&Vt[r0 * LDH + s0] = pv0;
        *(half8*)&Vt[r1 * LDH + s0] = pv1;
        if (j0 + BN < N_) {
            pk0h = *(const half8*)(kgh + (size_t)(j0 + BN + r0) * C_ + s0);
            pk1h = *(const half8*)(kgh + (size_t)(j0 + BN + r1) * C_ + s0);
            pk0l = *(const half8*)(kgl + (size_t)(j0 + BN + r0) * C_ + s0);
            pk1l = *(const half8*)(kgl + (size_t)(j0 + BN + r1) * C_ + s0);
            pv0  = *(const half8*)(vtg + (size_t)r0 * N_ + j0 + BN + s0);
            pv1  = *(const half8*)(vtg + (size_t)r1 * N_ + j0 + BN + s0);
        }
        __syncthreads();
        f32x4 S[4];
        #pragma unroll
        for (int s = 0; s < 4; s++) {
            half8 bh0 = *(half8*)&KQh[(s * 16 + lc) * LDH + 0 + quad * 8];
            half8 bh1 = *(half8*)&KQh[(s * 16 + lc) * LDH + 32 + quad * 8];
            half8 bl0 = *(half8*)&KQl[(s * 16 + lc) * LDH + 0 + quad * 8];
            half8 bl1 = *(half8*)&KQl[(s * 16 + lc) * LDH + 32 + quad * 8];
            f32x4 acc = (f32x4){0.f, 0.f, 0.f, 0.f};
            acc = __builtin_amdgcn_mfma_f32_16x16x32_f16(qa0, bh0, acc, 0, 0, 0);
            acc = __builtin_amdgcn_mfma_f32_16x16x32_f16(qa1, bh1, acc, 0, 0, 0);
            acc = __builtin_amdgcn_mfma_f32_16x16x32_f16(qa0, bl0, acc, 0, 0, 0);
            acc = __builtin_amdgcn_mfma_f32_16x16x32_f16(qa1, bl1, acc, 0, 0, 0);
            acc = __builtin_amdgcn_mfma_f32_16x16x32_f16(ql0, bh0, acc, 0, 0, 0);
            acc = __builtin_amdgcn_mfma_f32_16x16x32_f16(ql1, bh1, acc, 0, 0, 0);
            S[s] = acc;
        }
        // p: direct fp32 store to attn (C-layout, 64B segments — L2 write-combines),
        // and fp16 copy into wave-private Ps rows for the PV A-fragment.
        #pragma unroll
        for (int s = 0; s < 4; s++) {
            #pragma unroll
            for (int r = 0; r < 4; r++) {
                float p = EXP2(S[s][r] - m_run[r]) * l_run[r];
                attng[(size_t)(w * 16 + quad * 4 + r) * N_ + j0 + s * 16 + lc] = p;
                Ps[(w * 16 + quad * 4 + r) * LDH + s * 16 + lc] = (_Float16)p;
            }
        }
        // PV: A-frag = own Ps rows (wave-private, in-wave lgkm ordering suffices)
        #pragma unroll
        for (int kn = 0; kn < 2; kn++) {
            half8 pa = *(half8*)&Ps[(w * 16 + lc) * LDH + kn * 32 + quad * 8];
            #pragma unroll
            for (int sc = 0; sc < 4; sc++) {
                half8 vb = *(half8*)&Vt[(sc * 16 + lc) * LDH + kn * 32 + quad * 8];
                Oacc[sc] = __builtin_amdgcn_mfma_f32_16x16x32_f16(pa, vb, Oacc[sc], 0, 0, 0);
            }
        }
    }

    // write O (fp32); C/D layout: row = quad*4+r, col = 16sc+lc
    float* og = out + base + (size_t)qb * C_;
    #pragma unroll
    for (int sc = 0; sc < 4; sc++) {
        #pragma unroll
        for (int r = 0; r < 4; r++) {
            og[(size_t)(w * 16 + quad * 4 + r) * C_ + sc * 16 + lc] = Oacc[sc][r];
        }
    }
}

extern "C" void kernel_launch(void* const* d_in, const int* in_sizes, int n_in,
                              void* d_out, int out_size, void* d_ws, size_t ws_size,
                              hipStream_t stream) {
    const float* q = (const float*)d_in[0];
    const float* k = (const float*)d_in[1];
    const float* v = (const float*)d_in[2];
    const float* a = (const float*)d_in[3];
    const size_t nelem = (size_t)B_ * H_ * N_ * C_;   // 4M
    _Float16* kup_hi = (_Float16*)d_ws;               // 8 MB
    _Float16* kup_lo = kup_hi + nelem;                // 8 MB
    _Float16* vtb    = kup_lo + nelem;                // 8 MB, v transposed fp16 [bh][c][n]
    float* out = (float*)d_out;
    float* attn = out + nelem;

    prep_kernel<<<dim3(B_ * N_), dim3(512), 0, stream>>>(k, v, a, kup_hi, kup_lo);
    transpose_v_kernel<<<dim3(B_ * H_, N_ / 64), dim3(256), 0, stream>>>(v, vtb);
    attn_kernel<<<dim3(B_ * H_, N_ / BM), dim3(256), 0, stream>>>(q, vtb, kup_hi, kup_lo, out, attn);
}